// Round 1
// baseline (94.353 us; speedup 1.0000x reference)
//
#include <hip/hip_runtime.h>
#include <hip/hip_bf16.h>

typedef __bf16 bf16x8 __attribute__((ext_vector_type(8)));
typedef float  f32x4  __attribute__((ext_vector_type(4)));

#define LRELU_ALPHA 0.2f

__device__ __forceinline__ float lrelu(float x) { return x > 0.f ? x : LRELU_ALPHA * x; }

// ---------------------------------------------------------------------------
// Kernel 1: h = inp @ W  (one row per block, 128 threads), plus f1 = h·a1,
// f2 = h·a2. h kept fp32 (residual path needs it).
// ---------------------------------------------------------------------------
__global__ __launch_bounds__(128) void gat_prep(
    const float* __restrict__ inp, const float* __restrict__ W,
    const float* __restrict__ a,
    float* __restrict__ h, float* __restrict__ f1, float* __restrict__ f2)
{
    const int r = blockIdx.x;            // global row 0..16383
    const int d = threadIdx.x;           // 0..127
    __shared__ float sIn[128];
    __shared__ float sRed[4];
    sIn[d] = inp[(size_t)r * 128 + d];
    __syncthreads();
    float acc = 0.f;
    #pragma unroll 8
    for (int k = 0; k < 128; ++k) acc += sIn[k] * W[k * 128 + d];
    h[(size_t)r * 128 + d] = acc;
    float t1 = acc * a[d];
    float t2 = acc * a[128 + d];
    #pragma unroll
    for (int m = 1; m < 64; m <<= 1) {
        t1 += __shfl_xor(t1, m);
        t2 += __shfl_xor(t2, m);
    }
    const int wave = d >> 6;
    if ((d & 63) == 0) { sRed[wave] = t1; sRed[2 + wave] = t2; }
    __syncthreads();
    if (d == 0) {
        f1[r] = sRed[0] + sRed[1];
        f2[r] = sRed[2] + sRed[3];
    }
}

// ---------------------------------------------------------------------------
// Kernel 2: per-batch max of f1 (exact softmax stabilizer bound)
// ---------------------------------------------------------------------------
__global__ __launch_bounds__(256) void gat_f1max(
    const float* __restrict__ f1, float* __restrict__ f1max)
{
    const int b = blockIdx.x;
    const int t = threadIdx.x;
    float m = -1e30f;
    for (int j = t; j < 2048; j += 256) m = fmaxf(m, f1[b * 2048 + j]);
    #pragma unroll
    for (int k = 1; k < 64; k <<= 1) m = fmaxf(m, __shfl_xor(m, k));
    __shared__ float sm[4];
    if ((t & 63) == 0) sm[t >> 6] = m;
    __syncthreads();
    if (t == 0) f1max[b] = fmaxf(fmaxf(sm[0], sm[1]), fmaxf(sm[2], sm[3]));
}

// ---------------------------------------------------------------------------
// Kernel 3: transpose h (fp32, [b][n][128]) -> hT (bf16, [b][128][2048])
// so the MFMA B-operand is a contiguous k-minor 16B load. LDS-tiled 64x64.
// ---------------------------------------------------------------------------
__global__ __launch_bounds__(256) void gat_transpose(
    const float* __restrict__ h, __bf16* __restrict__ hT)
{
    __shared__ __bf16 tile[64][72];      // padded
    const int tid = threadIdx.x;
    const int bidx = blockIdx.x;         // 8 * 32 * 2 = 512 blocks
    const int b  = bidx >> 6;
    const int tI = bidx & 63;
    const int n0 = (tI >> 1) << 6;
    const int d0 = (tI & 1) << 6;
    #pragma unroll
    for (int pass = 0; pass < 2; ++pass) {
        int row = (tid >> 3) + (pass << 5);     // n within tile
        int c   = (tid & 7) << 3;               // d within tile
        const float* src = h + (size_t)(b * 2048 + n0 + row) * 128 + d0 + c;
        float4 v0 = *(const float4*)src;
        float4 v1 = *(const float4*)(src + 4);
        __bf16* tp = &tile[row][c];
        tp[0]=(__bf16)v0.x; tp[1]=(__bf16)v0.y; tp[2]=(__bf16)v0.z; tp[3]=(__bf16)v0.w;
        tp[4]=(__bf16)v1.x; tp[5]=(__bf16)v1.y; tp[6]=(__bf16)v1.z; tp[7]=(__bf16)v1.w;
    }
    __syncthreads();
    #pragma unroll
    for (int pass = 0; pass < 2; ++pass) {
        int dd = (tid >> 3) + (pass << 5);      // d within tile
        int nn = (tid & 7) << 3;                // n within tile
        union { __bf16 e[8]; bf16x8 v; } u;
        #pragma unroll
        for (int x = 0; x < 8; ++x) u.e[x] = tile[nn + x][dd];
        *(bf16x8*)(hT + ((size_t)(b * 128 + d0 + dd) << 11) + n0 + nn) = u.v;
    }
}

// ---------------------------------------------------------------------------
// Kernel 4: fused masked-softmax attention + PV (MFMA) + elu + residual.
// Block: 512 threads (8 waves), owns 32 i-rows of one batch.
// Wave w owns output cols [w*16, w*16+16). j-loop: 64 tiles of 32.
// Single pass, no online rescale (p = exp(e - M_i) <= 1 exactly).
// ---------------------------------------------------------------------------
__global__ __launch_bounds__(512) void gat_attn(
    const int* __restrict__ adj, const float* __restrict__ h,
    const __bf16* __restrict__ hT, const float* __restrict__ f1g,
    const float* __restrict__ f2g, const float* __restrict__ f1maxg,
    float* __restrict__ out)
{
    const int bid = blockIdx.x;          // 8 * 64 = 512 blocks
    const int b  = bid >> 6;
    const int i0 = (bid & 63) << 5;
    const int tid  = threadIdx.x;
    const int il   = tid >> 5;           // 0..15 (i within half-tile)
    const int jl   = tid & 31;           // j within j-tile
    const int lane = tid & 63;
    const int w    = tid >> 6;           // wave 0..7

    __shared__ float f1s[2048];
    __shared__ alignas(16) __bf16 P[32][40];   // padded to 80B rows (16B-aligned)
    __shared__ float lsum[32];

    for (int idx = tid; idx < 2048; idx += 512) f1s[idx] = f1g[b * 2048 + idx];

    const float fm   = f1maxg[b];
    const float f2v0 = f2g[b * 2048 + i0 + il];
    const float f2v1 = f2g[b * 2048 + i0 + il + 16];
    const float M0 = lrelu(f2v0 + fm);
    const float M1 = lrelu(f2v1 + fm);

    const int* ajp0 = adj + ((size_t)(b * 2048 + i0 + il)) * 2048 + jl;
    const int* ajp1 = ajp0 + (size_t)16 * 2048;

    // B-fragment base: wave w covers cols w*16 + (lane&15); k-minor layout.
    const int kb = (lane >> 4) << 3;     // k sub-offset 0/8/16/24
    const __bf16* hTb = hT + ((size_t)(b * 128 + (w << 4) + (lane & 15)) << 11) + kb;

    f32x4 acc0 = {0.f, 0.f, 0.f, 0.f};
    f32x4 acc1 = {0.f, 0.f, 0.f, 0.f};
    float ps0 = 0.f, ps1 = 0.f;

    int a0 = ajp0[0], a1 = ajp1[0];
    bf16x8 Bf = *(const bf16x8*)hTb;

    __syncthreads();                     // f1s ready

    for (int t = 0; t < 64; ++t) {
        const int tn = (t + 1) & 63;     // wrap: avoids branch, always in-bounds
        int na0 = ajp0[tn * 32];
        int na1 = ajp1[tn * 32];
        bf16x8 nBf = *(const bf16x8*)(hTb + tn * 32);

        float f1v = f1s[t * 32 + jl];
        float p0 = (a0 > 0) ? __expf(lrelu(f2v0 + f1v) - M0) : 0.f;
        float p1 = (a1 > 0) ? __expf(lrelu(f2v1 + f1v) - M1) : 0.f;
        __bf16 pb0 = (__bf16)p0, pb1 = (__bf16)p1;
        ps0 += (float)pb0;               // denominator from the SAME bf16 values
        ps1 += (float)pb1;
        P[il][jl]      = pb0;
        P[il + 16][jl] = pb1;
        __syncthreads();

        bf16x8 A0 = *(const bf16x8*)&P[lane & 15][kb];
        bf16x8 A1 = *(const bf16x8*)&P[16 + (lane & 15)][kb];
        acc0 = __builtin_amdgcn_mfma_f32_16x16x32_bf16(A0, Bf, acc0, 0, 0, 0);
        acc1 = __builtin_amdgcn_mfma_f32_16x16x32_bf16(A1, Bf, acc1, 0, 0, 0);
        __syncthreads();

        a0 = na0; a1 = na1; Bf = nBf;
    }

    // denominator: reduce ps over the 32 j-lanes (lane bits 0..4)
    #pragma unroll
    for (int m = 1; m < 32; m <<= 1) {
        ps0 += __shfl_xor(ps0, m);
        ps1 += __shfl_xor(ps1, m);
    }
    if (jl == 0) { lsum[il] = ps0; lsum[il + 16] = ps1; }
    __syncthreads();

    // epilogue: normalize, elu, + h (fp32)
    const int col = (w << 4) + (lane & 15);
    #pragma unroll
    for (int rf = 0; rf < 2; ++rf) {
        f32x4 acc = rf ? acc1 : acc0;
        #pragma unroll
        for (int r = 0; r < 4; ++r) {
            int row = (rf << 4) + ((lane >> 4) << 2) + r;
            float v = acc[r] / lsum[row];
            float e = (v > 0.f) ? v : (__expf(v) - 1.f);
            size_t gi = ((size_t)(b * 2048 + i0 + row)) * 128 + col;
            out[gi] = e + h[gi];
        }
    }
}

// ---------------------------------------------------------------------------
extern "C" void kernel_launch(void* const* d_in, const int* in_sizes, int n_in,
                              void* d_out, int out_size, void* d_ws, size_t ws_size,
                              hipStream_t stream)
{
    const float* inp = (const float*)d_in[0];
    const int*   adj = (const int*)d_in[1];
    const float* W   = (const float*)d_in[2];
    const float* a   = (const float*)d_in[3];
    float* out = (float*)d_out;

    // workspace layout (needs ~12.7 MB)
    char* ws = (char*)d_ws;
    float*  h     = (float*)ws;                          // 8 MB
    __bf16* hT    = (__bf16*)(ws + 8388608);             // 4 MB
    float*  f1    = (float*)(ws + 8388608 + 4194304);    // 64 KB
    float*  f2    = (float*)(ws + 8388608 + 4194304 + 65536);
    float*  f1max = (float*)(ws + 8388608 + 4194304 + 131072);

    gat_prep<<<16384, 128, 0, stream>>>(inp, W, a, h, f1, f2);
    gat_f1max<<<8, 256, 0, stream>>>(f1, f1max);
    gat_transpose<<<512, 256, 0, stream>>>(h, hT);
    gat_attn<<<512, 512, 0, stream>>>(adj, h, hT, f1, f2, f1max, out);
}